// Round 9
// baseline (617.331 us; speedup 1.0000x reference)
//
#include <hip/hip_runtime.h>

#define D 64
#define BN_EPS 1e-5f
#define NPART 8

// ---------------------------------------------------------------------------
// CSR build — hist/fill partitioned by dst range so each partition's scattered
// writes/atomics stay in one XCD's L2 (blockIdx%8 == XCD round-robin) and merge
// before writeback.
// ---------------------------------------------------------------------------
__global__ __launch_bounds__(256) void hist_kernel(const int* __restrict__ edst, int E, int N,
                                                   int* __restrict__ counts, uint* __restrict__ hwBase) {
    // zero the dummy gather row (hW row N, 128 B) once per call
    if (blockIdx.x == gridDim.x - 1 && threadIdx.x < 32)
        hwBase[(size_t)N * 32 + threadIdx.x] = 0u;
    int part = blockIdx.x & (NPART - 1);
    int bIdx = blockIdx.x / NPART;
    int nblk = gridDim.x / NPART;
    int partN = (N + NPART - 1) / NPART;
    int nlo = part * partN;
    int nhi = min(N, nlo + partN);
    int E4 = E >> 2;
    const int4* d4 = (const int4*)edst;
    for (int i = bIdx * 256 + threadIdx.x; i < E4; i += nblk * 256) {
        int4 d = d4[i];
        if (d.x >= nlo && d.x < nhi) atomicAdd(&counts[d.x], 1);
        if (d.y >= nlo && d.y < nhi) atomicAdd(&counts[d.y], 1);
        if (d.z >= nlo && d.z < nhi) atomicAdd(&counts[d.z], 1);
        if (d.w >= nlo && d.w < nhi) atomicAdd(&counts[d.w], 1);
    }
    if (blockIdx.x == 0) {
        for (int e = (E4 << 2) + threadIdx.x; e < E; e += 256) atomicAdd(&counts[edst[e]], 1);
    }
}

// inclusive block scan of counts; rowptr[i+1] = incl(i) (pre-offset); bsums[b] = block total
// also emits dinv[i] = rsqrt(count+1)  (self loop included)
__global__ void scan1_kernel(const int* __restrict__ counts, int N,
                             int* __restrict__ rowptr, int* __restrict__ bsums,
                             float* __restrict__ dinv) {
    __shared__ int s[256];
    int i = blockIdx.x * 256 + threadIdx.x;
    int v = (i < N) ? counts[i] : 0;
    s[threadIdx.x] = v;
    __syncthreads();
    for (int off = 1; off < 256; off <<= 1) {
        int t = (threadIdx.x >= off) ? s[threadIdx.x - off] : 0;
        __syncthreads();
        s[threadIdx.x] += t;
        __syncthreads();
    }
    if (i < N) {
        rowptr[i + 1] = s[threadIdx.x];
        dinv[i] = rsqrtf((float)(v + 1));
    }
    if (threadIdx.x == 255) bsums[blockIdx.x] = s[255];
}

__global__ void scan2_kernel(const int* __restrict__ bsums, int nb, int* __restrict__ boff) {
    __shared__ int s[512];
    int v = (threadIdx.x < nb) ? bsums[threadIdx.x] : 0;
    s[threadIdx.x] = v;
    __syncthreads();
    for (int off = 1; off < 512; off <<= 1) {
        int t = (threadIdx.x >= off) ? s[threadIdx.x - off] : 0;
        __syncthreads();
        s[threadIdx.x] += t;
        __syncthreads();
    }
    if (threadIdx.x < nb) boff[threadIdx.x] = s[threadIdx.x] - v; // exclusive
}

// apply block offsets; also seed cursor = final rowptr
__global__ void scan3_kernel(int* __restrict__ rowptr, const int* __restrict__ boff, int N,
                             int* __restrict__ cursor) {
    int i = blockIdx.x * 256 + threadIdx.x;
    if (i == 0) { rowptr[0] = 0; cursor[0] = 0; }
    if (i < N) {
        int v = rowptr[i + 1] + boff[i >> 8];
        rowptr[i + 1] = v;
        if (i + 1 < N) cursor[i + 1] = v;
    }
}

__global__ __launch_bounds__(256) void fill_kernel(const int* __restrict__ esrc,
                                                   const int* __restrict__ edst, int E, int N,
                                                   int* __restrict__ cursor, int* __restrict__ col) {
    int part = blockIdx.x & (NPART - 1);
    int bIdx = blockIdx.x / NPART;
    int nblk = gridDim.x / NPART;
    int partN = (N + NPART - 1) / NPART;
    int nlo = part * partN;
    int nhi = min(N, nlo + partN);
    int E4 = E >> 2;
    const int4* d4 = (const int4*)edst;
    const int4* s4 = (const int4*)esrc;
    for (int i = bIdx * 256 + threadIdx.x; i < E4; i += nblk * 256) {
        int4 d = d4[i];
        bool mx = (d.x >= nlo) & (d.x < nhi);
        bool my = (d.y >= nlo) & (d.y < nhi);
        bool mz = (d.z >= nlo) & (d.z < nhi);
        bool mw = (d.w >= nlo) & (d.w < nhi);
        if (mx | my | mz | mw) {
            int4 s = s4[i];
            if (mx) col[atomicAdd(&cursor[d.x], 1)] = s.x;
            if (my) col[atomicAdd(&cursor[d.y], 1)] = s.y;
            if (mz) col[atomicAdd(&cursor[d.z], 1)] = s.z;
            if (mw) col[atomicAdd(&cursor[d.w], 1)] = s.w;
        }
    }
    if (blockIdx.x == 0) {
        for (int e = (E4 << 2) + threadIdx.x; e < E; e += 256) {
            int d = edst[e];
            col[atomicAdd(&cursor[d], 1)] = esrc[e];
        }
    }
}

// ---------------------------------------------------------------------------
// Per-layer kernels
// ---------------------------------------------------------------------------
__device__ __forceinline__ ushort f2bf(float x) {
    uint u = __float_as_uint(x);
    u += 0x7fffu + ((u >> 16) & 1u); // RNE
    return (ushort)(u >> 16);
}
__device__ __forceinline__ float bflo(uint u) { return __uint_as_float(u << 16); }
__device__ __forceinline__ float bfhi(uint u) { return __uint_as_float(u & 0xffff0000u); }

// Register-blocked GEMM: block = 128 rows x 64 cols, thread = 8x4 outputs.
// out_bf16[r][j] = dinv[r] * sum_k act(in[r][k]) * W[k][j]; act = BN affine+relu (BN path),
// with the BN scale/shift computed in-block from the previous layer's raw stats.
// Full-row layout [N+1][64] bf16.
template <bool BN>
__global__ __launch_bounds__(256) void gemm_kernel(const float* __restrict__ inF,
                                                   const ushort* __restrict__ inB,
                                                   const float* __restrict__ W,
                                                   const float* __restrict__ stats, // prev layer sum/sumsq
                                                   const float* __restrict__ gamma,
                                                   const float* __restrict__ beta,
                                                   const float* __restrict__ dinv,
                                                   ushort* __restrict__ outb, int N) {
    __shared__ float in_t[D][128]; // 32 KB, [k][row]
    __shared__ float Wl[D][D];     // 16 KB, [k][col]
    __shared__ float bnl[128];
    int t = threadIdx.x;
    if (BN) {
        if (t < 64) {
            float invN = 1.f / (float)N;
            float mean = stats[t] * invN;
            float var  = stats[64 + t] * invN - mean * mean;
            float sc   = gamma[t] * rsqrtf(var + BN_EPS);
            bnl[t]      = sc;
            bnl[64 + t] = beta[t] - mean * sc;
        }
        __syncthreads();
    }
    for (int i = t; i < D * D / 4; i += 256)
        ((float4*)&Wl[0][0])[i] = ((const float4*)W)[i];

    int r = t >> 1;               // 0..127
    int fbase = (t & 1) * 32;
    int grow = blockIdx.x * 128 + r;
    if (BN) {
        if (grow < N) {
            const uint* src = (const uint*)(inB + (size_t)grow * D + fbase);
#pragma unroll
            for (int j = 0; j < 16; ++j) {
                uint u = src[j];
                int f = fbase + 2 * j;
                in_t[f][r]     = fmaxf(fmaf(bflo(u), bnl[f],     bnl[64 + f]),     0.f);
                in_t[f + 1][r] = fmaxf(fmaf(bfhi(u), bnl[f + 1], bnl[64 + f + 1]), 0.f);
            }
        } else {
#pragma unroll
            for (int j = 0; j < 32; ++j) in_t[fbase + j][r] = 0.f;
        }
    } else {
        if (grow < N) {
            const float4* src = (const float4*)(inF + (size_t)grow * D + fbase);
#pragma unroll
            for (int j = 0; j < 8; ++j) {
                float4 v = src[j];
                int f = fbase + 4 * j;
                in_t[f][r] = v.x; in_t[f + 1][r] = v.y; in_t[f + 2][r] = v.z; in_t[f + 3][r] = v.w;
            }
        } else {
#pragma unroll
            for (int j = 0; j < 32; ++j) in_t[fbase + j][r] = 0.f;
        }
    }
    __syncthreads();

    int rg = t & 15;  // rows 8*rg .. 8*rg+7
    int cg = t >> 4;  // cols 4*cg .. 4*cg+3
    float acc[8][4];
#pragma unroll
    for (int i = 0; i < 8; ++i)
#pragma unroll
        for (int j = 0; j < 4; ++j) acc[i][j] = 0.f;

#pragma unroll 8
    for (int k = 0; k < D; ++k) {
        float4 a0 = *(const float4*)&in_t[k][8 * rg];
        float4 a1 = *(const float4*)&in_t[k][8 * rg + 4];
        float4 b  = *(const float4*)&Wl[k][4 * cg];
        float ar[8] = {a0.x, a0.y, a0.z, a0.w, a1.x, a1.y, a1.z, a1.w};
        float br[4] = {b.x, b.y, b.z, b.w};
#pragma unroll
        for (int i = 0; i < 8; ++i)
#pragma unroll
            for (int j = 0; j < 4; ++j)
                acc[i][j] = fmaf(ar[i], br[j], acc[i][j]);
    }

#pragma unroll
    for (int i = 0; i < 8; ++i) {
        int row = blockIdx.x * 128 + 8 * rg + i;
        if (row < N) {
            float dn = dinv[row];
            uint2 pk;
            pk.x = ((uint)f2bf(acc[i][1] * dn) << 16) | (uint)f2bf(acc[i][0] * dn);
            pk.y = ((uint)f2bf(acc[i][3] * dn) << 16) | (uint)f2bf(acc[i][2] * dn);
            *(uint2*)(outb + (size_t)row * D + 4 * cg) = pk;
        }
    }
}

// Full-row aggregation, low-VGPR shape: wave = 1 node; 8 groups x 8 lanes; each
// group owns one edge and issues TWO uint2 loads (both 64 B halves of the 128 B
// row, same index). Unroll 2 -> 4 edges x 8 lines = 32 lines in flight per wave.
// OOB slots read the zero dummy row (index N). Cross-group combine = 3 shfl_xor.
// outB[n] = dinv[n] * (hW[n] + sum_src hW[src]); fused BN stats -> atomics.
__global__ __launch_bounds__(256) void agg_kernel(const ushort* __restrict__ hW,
                                                  const int* __restrict__ rowptr,
                                                  const int* __restrict__ col,
                                                  const float* __restrict__ dinv,
                                                  ushort* __restrict__ outB,
                                                  float* __restrict__ stats, int N) {
    const uint2* hw2 = (const uint2*)hW; // row stride = 16 uint2
    uint2* out2 = (uint2*)outB;
    int t = threadIdx.x;
    int lane = t & 63;
    int wv   = t >> 6;       // 0..3
    int g    = lane >> 3;    // group 0..7 (edge slot)
    int j    = lane & 7;     // feature quad within half
    float sa[4] = {0.f,0.f,0.f,0.f}, sb[4] = {0.f,0.f,0.f,0.f};
    float qa[4] = {0.f,0.f,0.f,0.f}, qb[4] = {0.f,0.f,0.f,0.f};
    int gw = blockIdx.x * 4 + wv;
    int nw = gridDim.x * 4;
    for (int n = gw; n < N; n += nw) {
        int e0 = rowptr[n], e1 = rowptr[n + 1];
        float a[4] = {0.f,0.f,0.f,0.f}, b[4] = {0.f,0.f,0.f,0.f};
        if (g == 0) {
            uint2 ua = hw2[(size_t)n * 16 + j];
            uint2 ub = hw2[(size_t)n * 16 + 8 + j];
            a[0] = bflo(ua.x); a[1] = bfhi(ua.x); a[2] = bflo(ua.y); a[3] = bfhi(ua.y);
            b[0] = bflo(ub.x); b[1] = bfhi(ub.x); b[2] = bflo(ub.y); b[3] = bfhi(ub.y);
        }
        int m = e1 - 1;
        for (int eb = e0; eb < e1; eb += 16) {
            int cc[2];
            uint2 ua[2], ub[2];
#pragma unroll
            for (int u = 0; u < 2; ++u) {
                int e = eb + 8 * u + g;
                bool ok = e < e1;
                int c = col[ok ? e : m];
                cc[u] = ok ? c : N; // dummy zero row when past end
            }
#pragma unroll
            for (int u = 0; u < 2; ++u) {
                ua[u] = hw2[(size_t)cc[u] * 16 + j];
                ub[u] = hw2[(size_t)cc[u] * 16 + 8 + j];
            }
#pragma unroll
            for (int u = 0; u < 2; ++u) {
                a[0] += bflo(ua[u].x); a[1] += bfhi(ua[u].x);
                a[2] += bflo(ua[u].y); a[3] += bfhi(ua[u].y);
                b[0] += bflo(ub[u].x); b[1] += bfhi(ub[u].x);
                b[2] += bflo(ub[u].y); b[3] += bfhi(ub[u].y);
            }
        }
#pragma unroll
        for (int k = 0; k < 4; ++k) {
            a[k] += __shfl(a[k], lane ^ 8);
            a[k] += __shfl(a[k], lane ^ 16);
            a[k] += __shfl(a[k], lane ^ 32);
            b[k] += __shfl(b[k], lane ^ 8);
            b[k] += __shfl(b[k], lane ^ 16);
            b[k] += __shfl(b[k], lane ^ 32);
        }
        if (g == 0) {
            float dn = dinv[n];
#pragma unroll
            for (int k = 0; k < 4; ++k) {
                a[k] *= dn; b[k] *= dn;
                sa[k] += a[k]; qa[k] += a[k] * a[k];
                sb[k] += b[k]; qb[k] += b[k] * b[k];
            }
            uint2 pka, pkb;
            pka.x = ((uint)f2bf(a[1]) << 16) | (uint)f2bf(a[0]);
            pka.y = ((uint)f2bf(a[3]) << 16) | (uint)f2bf(a[2]);
            pkb.x = ((uint)f2bf(b[1]) << 16) | (uint)f2bf(b[0]);
            pkb.y = ((uint)f2bf(b[3]) << 16) | (uint)f2bf(b[2]);
            out2[(size_t)n * 16 + j]     = pka;
            out2[(size_t)n * 16 + 8 + j] = pkb;
        }
    }
    // block-level BN stats: features 0..63 sums, 64..127 sumsq -> atomics into stats[128]
    __shared__ float red[4][128];
    if (g == 0) {
#pragma unroll
        for (int k = 0; k < 4; ++k) {
            red[wv][4 * j + k]           = sa[k];
            red[wv][32 + 4 * j + k]      = sb[k];
            red[wv][64 + 4 * j + k]      = qa[k];
            red[wv][96 + 4 * j + k]      = qb[k];
        }
    }
    __syncthreads();
    if (t < 128) {
        atomicAdd(&stats[t], red[0][t] + red[1][t] + red[2][t] + red[3][t]);
    }
}

// final: read bf16 pre-norm h, apply BN (computed in-block from stats) + ReLU, write fp32
__global__ __launch_bounds__(256) void norm_relu_kernel(const uint* __restrict__ B32,
                                                        const float* __restrict__ stats,
                                                        const float* __restrict__ gamma,
                                                        const float* __restrict__ beta,
                                                        int N, float2* __restrict__ out, int n32) {
    __shared__ float bnl[128];
    int t = threadIdx.x;
    if (t < 64) {
        float invN = 1.f / (float)N;
        float mean = stats[t] * invN;
        float var  = stats[64 + t] * invN - mean * mean;
        float sc   = gamma[t] * rsqrtf(var + BN_EPS);
        bnl[t]      = sc;
        bnl[64 + t] = beta[t] - mean * sc;
    }
    __syncthreads();
    int i = blockIdx.x * 256 + t;
    if (i < n32) {
        int f2 = (i & 31) * 2;
        uint u = B32[i];
        float a = fmaxf(fmaf(bflo(u), bnl[f2],     bnl[64 + f2]),     0.f);
        float b = fmaxf(fmaf(bfhi(u), bnl[f2 + 1], bnl[64 + f2 + 1]), 0.f);
        out[i] = make_float2(a, b);
    }
}

// ---------------------------------------------------------------------------
extern "C" void kernel_launch(void* const* d_in, const int* in_sizes, int n_in,
                              void* d_out, int out_size, void* d_ws, size_t ws_size,
                              hipStream_t stream) {
    const float* x      = (const float*)d_in[0];
    const int*   ei     = (const int*)d_in[1];
    const float* Ws     = (const float*)d_in[2];
    // d_in[3] = bs: cancels exactly under training-mode BatchNorm
    const float* gammas = (const float*)d_in[4];
    const float* betas  = (const float*)d_in[5];

    const int N = in_sizes[0] / D;           // 100000
    const int E = in_sizes[1] / 2;           // 1250000
    const int DEPTH = in_sizes[2] / (D * D); // 4

    const int* esrc = ei;
    const int* edst = ei + E;

    char* w = (char*)d_ws;
    size_t off = 0;
    auto alloc = [&](size_t bytes) {
        void* p = w + off;
        off = (off + bytes + 255) & ~(size_t)255;
        return p;
    };
    ushort* hW     = (ushort*)alloc((size_t)(N + 1) * D * sizeof(ushort)); // 12.8 MB bf16 (+dummy row)
    ushort* B      = (ushort*)alloc((size_t)N * D * sizeof(ushort));       // 12.8 MB bf16 pre-norm h
    int*    counts = (int*)alloc((size_t)N * sizeof(int));                 // | contiguous with
    float*  stats  = (float*)alloc(4 * 128 * sizeof(float));               // | per-layer stats
    int*    rowptr = (int*)alloc((size_t)(N + 1) * sizeof(int));
    int*    cursor = (int*)alloc((size_t)(N + 1) * sizeof(int));
    float*  dinv   = (float*)alloc((size_t)N * sizeof(float));
    int*    col    = (int*)alloc((size_t)E * sizeof(int));
    int*    bsums  = (int*)alloc(512 * sizeof(int));
    int*    boff   = (int*)alloc(512 * sizeof(int));

    const int nbScan = (N + 255) / 256; // 391

    // single memset covers counts + (alignment pad) + stats
    size_t zbytes = (char*)(stats + 4 * 128) - (char*)counts;
    hipMemsetAsync(counts, 0, zbytes, stream);

    // ---- degree + CSR ----
    hist_kernel<<<1024, 256, 0, stream>>>(edst, E, N, counts, (uint*)hW);
    scan1_kernel<<<nbScan, 256, 0, stream>>>(counts, N, rowptr, bsums, dinv);
    scan2_kernel<<<1, 512, 0, stream>>>(bsums, nbScan, boff);
    scan3_kernel<<<nbScan, 256, 0, stream>>>(rowptr, boff, N, cursor);
    fill_kernel<<<1024, 256, 0, stream>>>(esrc, edst, E, N, cursor, col);

    // ---- layers ----
    const int gemmBlocks = (N + 127) / 128; // 782
    const int aggBlocks  = 2048;
    for (int l = 0; l < DEPTH; ++l) {
        const float* W = Ws + (size_t)l * D * D;
        if (l == 0)
            gemm_kernel<false><<<gemmBlocks, 256, 0, stream>>>(x, B, W,
                stats, gammas, betas, dinv, hW, N);
        else
            gemm_kernel<true><<<gemmBlocks, 256, 0, stream>>>(x, B, W,
                stats + (size_t)(l - 1) * 128, gammas + (l - 1) * D, betas + (l - 1) * D,
                dinv, hW, N);
        agg_kernel<<<aggBlocks, 256, 0, stream>>>(hW, rowptr, col, dinv, B,
                                                  stats + (size_t)l * 128, N);
    }
    // final BN + relu: bf16 B -> fp32 d_out
    norm_relu_kernel<<<(N * 32 + 255) / 256, 256, 0, stream>>>((const uint*)B,
        stats + (size_t)(DEPTH - 1) * 128, gammas + (DEPTH - 1) * D, betas + (DEPTH - 1) * D,
        N, (float2*)d_out, N * 32);
}